// Round 21
// baseline (1618.023 us; speedup 1.0000x reference)
//
#include <hip/hip_runtime.h>
#include <math.h>

#define BB 256
#define TT 512
#define DD 256
#define HH 512
#define SS 8
#define G4H 2048
#define BH (BB*HH)          // 131072
#define OUT_BASE ((size_t)BB*TT*DD)
#define NGRP 16
#define GR 16               // batch rows per group
#define XSLOT_U32 4096      // 16 KB per group-slot: [role 0..7][16 rows][32 u32]
#define FSTRIDE 16          // ints between flags (64 B): one cache line per flag

typedef _Float16 f16;
typedef __attribute__((ext_vector_type(8))) _Float16 f16x8;
typedef __attribute__((ext_vector_type(4))) float    f32x4;

__device__ __forceinline__ float sigm(float x) { return 1.f / (1.f + __expf(-x)); }
__device__ __forceinline__ float ftanh(float x) {
  x = fminf(15.f, fmaxf(-15.f, x));
  float e = __expf(-2.f * x);
  return (1.f - e) / (1.f + e);
}

// ---------------- prep kernels ----------------

__global__ __launch_bounds__(256) void prep_wbig16(
    const float* __restrict__ W_ih, const float* __restrict__ W_hh,
    const float* __restrict__ W_lin, f16* __restrict__ Wbig16)
{
  __shared__ float As[64][20];
  __shared__ float Bs[16][68];
  const int n0 = blockIdx.x * 64;
  const int j0 = blockIdx.y * 64;
  const int tid = threadIdx.x;
  const int tn = tid >> 4, tj = tid & 15;
  float acc[4][4] = {};
  for (int k0 = 0; k0 < DD; k0 += 16) {
    { int r = tid >> 2, c = (tid & 3) * 4;
      *(float4*)&As[r][c] = *(const float4*)&W_ih[(size_t)(n0 + r) * DD + k0 + c]; }
    { int r = tid >> 4, c = (tid & 15) * 4;
      *(float4*)&Bs[r][c] = *(const float4*)&W_lin[(size_t)(k0 + r) * HH + j0 + c]; }
    __syncthreads();
    #pragma unroll
    for (int k = 0; k < 16; ++k) {
      float a[4], bv[4];
      #pragma unroll
      for (int i = 0; i < 4; ++i) a[i] = As[tn*4+i][k];
      #pragma unroll
      for (int m = 0; m < 4; ++m) bv[m] = Bs[k][tj*4+m];
      #pragma unroll
      for (int i = 0; i < 4; ++i)
        #pragma unroll
        for (int m = 0; m < 4; ++m)
          acc[i][m] = fmaf(a[i], bv[m], acc[i][m]);
    }
    __syncthreads();
  }
  #pragma unroll
  for (int i = 0; i < 4; ++i) {
    int n = n0 + tn*4 + i;
    #pragma unroll
    for (int m = 0; m < 4; ++m) {
      int j = j0 + tj*4 + m;
      Wbig16[(size_t)n*HH + j] = (f16)(acc[i][m] + W_hh[(size_t)n*HH + j]);
    }
  }
}

__global__ void prep_bias(const float* __restrict__ b_ih, const float* __restrict__ b_hh,
                          const float* __restrict__ W_ih, const float* __restrict__ b_lin,
                          float* __restrict__ bias0, float* __restrict__ bias1)
{
  int n = blockIdx.x * 256 + threadIdx.x;   // grid 8
  float s = b_ih[n] + b_hh[n];
  float d = 0.f;
  for (int k = 0; k < DD; ++k) d = fmaf(W_ih[(size_t)n*DD + k], b_lin[k], d);
  bias0[n] = s;
  bias1[n] = s + d;
}

#define NIH (G4H*DD)
#define NHH (G4H*HH)
__global__ void prep_cvtw(const float* __restrict__ W_ih, const float* __restrict__ W_hh,
                          const float* __restrict__ W_lin,
                          f16* __restrict__ Wih16, f16* __restrict__ Whh16,
                          f16* __restrict__ Wlin16)
{
  int e = blockIdx.x * 256 + threadIdx.x;   // grid 6656
  if (e < NIH) Wih16[e] = (f16)W_ih[e];
  else if (e < NIH + NHH) Whh16[e - NIH] = (f16)W_hh[e - NIH];
  else Wlin16[e - NIH - NHH] = (f16)W_lin[e - NIH - NHH];
}

__global__ void prep_init(const float* __restrict__ x0, const float* __restrict__ h0,
                          const float* __restrict__ c0,
                          const int* __restrict__ w1, const int* __restrict__ w2,
                          float* __restrict__ bh, float* __restrict__ bc,
                          f16* __restrict__ x0hi, f16* __restrict__ x0lo,
                          f16* __restrict__ h0hi, f16* __restrict__ h0lo,
                          float4* __restrict__ stepc,
                          int* __restrict__ flags)
{
  int e = blockIdx.x * 256 + threadIdx.x;   // grid 4096 -> 1048576
  int r = e & (BH - 1);
  bh[e] = h0[r];
  bc[e] = c0[r];
  if (e < BH) {
    float v = h0[e];
    f16 hi = (f16)v;
    h0hi[e] = hi;
    h0lo[e] = (f16)(v - (float)hi);
  }
  if (e < BB*DD) {
    int b = e >> 8, d = e & 255;
    float v = x0[(size_t)b*(TT*DD) + d];
    f16 hi = (f16)v;
    x0hi[e] = hi;
    x0lo[e] = (f16)(v - (float)hi);
  }
  if (e < TT) {
    float a1 = (float)w1[e], a2 = (float)w2[e];
    stepc[e] = make_float4(a1, a2, 1.f / (a1 + a2), 0.f);
  }
  if (e < 4096) flags[e] = 0;
}

// ---------------- persistent main kernel ----------------

// Stage role-w stripe (2 KB: 16 rows x 32 u32) of one slot into LDS via
// global_load_lds. Source carries the bank swizzle: LDS unit q (row=q>>3,
// phys-u=q&7) is filled from logical unit (q&7)^(row&7). LDS dest linear.
__device__ __forceinline__ void stage_stripe(const unsigned* __restrict__ Xs,
                                             int w, f16* lds, int lane) {
  #pragma unroll
  for (int i = 0; i < 2; ++i) {
    int q = i * 64 + lane;              // unit 0..127 (16 B each)
    int row = q >> 3, u = q & 7;
    const char* src = (const char*)Xs + w * 2048 + row * 128 +
                      ((u ^ (row & 7)) << 4);
    __builtin_amdgcn_global_load_lds(
        (const __attribute__((address_space(1))) void*)src,
        (__attribute__((address_space(3))) void*)((char*)lds + w * 2048 + i * 1024),
        16, 0, 0x11 /* sc0|sc1 */);
  }
}

// K=512 quad-N-tile 16x16x32 MFMA GEMM from role-major swizzled LDS.
// A-frag: row = lane&15, k = ks*32 + (lane>>4)*8 -> role = ks>>1,
// logical u = ((ks&1)<<2) + kc, phys u' = u ^ (row&7). One A-read feeds 4 MFMAs.
__device__ __forceinline__ void gemm4(const f16x8 (&w)[4][16], const f16* lds,
                                      int lane, f32x4 (&acc)[4]) {
  const int r  = lane & 15;
  const int kc = lane >> 4;            // 0..3
  #pragma unroll
  for (int ks = 0; ks < 16; ++ks) {
    int role_k = ks >> 1;
    int u = ((ks & 1) << 2) + kc;
    int off = role_k * 2048 + r * 128 + ((u ^ (r & 7)) << 4);
    f16x8 a = *(const f16x8*)((const char*)lds + off);
    #pragma unroll
    for (int g = 0; g < 4; ++g)
      acc[g] = __builtin_amdgcn_mfma_f32_16x16x32_f16(a, w[g][ks], acc[g], 0, 0, 0);
  }
}

// 144 blocks x 256 threads (4 waves), 1 wave/SIMD (512-VGPR budget).
// bid 0..127: gates. grp = bid&15 owns batch rows [16g,16g+16); role = bid>>4
//   owns j-slice [64r,64r+64). Wave wv owns j-sub [64r+16wv, +16) x ALL 4
//   gates (4 N-tiles) -> gate-combine is fully register-local (no gbuf).
// bid 128..143: out block per group; wave wv owns d-cols [64wv, 64wv+64).
// Flags: one 64-B line per flag. Wave wv stages stripes {2wv, 2wv+1}; its
// lanes 0/1 poll those two flags concurrently (1 poller per line per block).
__global__ __launch_bounds__(256, 1) void lstm_persist(
    const f16* __restrict__ x0hi, const f16* __restrict__ x0lo,
    const f16* __restrict__ h0hi, const f16* __restrict__ h0lo,
    const float* __restrict__ c0,
    const f16* __restrict__ Wih16, const f16* __restrict__ Whh16,
    const f16* __restrict__ Wbig16, const f16* __restrict__ Wlin16,
    const float* __restrict__ bias0, const float* __restrict__ bias1,
    const float* __restrict__ b_lin,
    const float4* __restrict__ stepc,
    unsigned* __restrict__ X,                 // 4 slots x 16 grp x XSLOT_U32
    float* __restrict__ bh, float* __restrict__ bc,
    int* __restrict__ flags,
    float* __restrict__ outp)
{
  __shared__ f16 LdsA[8192];        // 16 KB: [role][16 rows][64 f16]

  const int tid  = threadIdx.x;     // 0..255
  const int lane = tid & 63;
  const int wv   = tid >> 6;            // wave 0..3
  const int bid  = blockIdx.x;
  const bool isG = bid < 128;
  const int grp  = isG ? (bid & 15) : (bid - 128);
  const int role = bid >> 4;            // gates only: 0..7
  const int b0   = grp * GR;
  const int r16  = lane & 15;
  const int kc   = lane >> 4;           // 0..3
  const int ksel = kc * 8;

  int* gflag = flags + grp * 9 * FSTRIDE;   // flag r at gflag[r*FSTRIDE]

  // ---- persistent W fragments: 4 N-tiles x K=512 -> 256 VGPR ----
  int rowG[4];
  const f16* wsrc;
  if (isG) {
    #pragma unroll
    for (int g = 0; g < 4; ++g) rowG[g] = g * 512 + role * 64 + wv * 16 + r16;
    wsrc = Wbig16;
  } else {
    #pragma unroll
    for (int g = 0; g < 4; ++g) rowG[g] = wv * 64 + g * 16 + r16;   // d-cols
    wsrc = Wlin16;
  }
  f16x8 wreg[4][16];
  #pragma unroll
  for (int g = 0; g < 4; ++g)
    #pragma unroll
    for (int ks = 0; ks < 16; ++ks)
      wreg[g][ks] = *(const f16x8*)(wsrc + (size_t)rowG[g] * HH + ks * 32 + ksel);

  if (isG) {
    // ---- per-lane epilogue constants: j fixed, 4 batch rows (m = kc*4+rg) ----
    const int jg = role * 64 + wv * 16 + r16;
    const int jl = wv * 16 + r16;                 // j within stripe
    const float bI = bias1[jg],        bF = bias1[512 + jg];
    const float bG = bias1[1024 + jg], bO = bias1[1536 + jg];
    int   eidx[4];
    float creg[4];
    #pragma unroll
    for (int rg = 0; rg < 4; ++rg) {
      eidx[rg] = (b0 + kc * 4 + rg) * HH + jg;
      creg[rg] = c0[eidx[rg]];
    }

    for (int t = 0; t < TT; ++t) {
      // skip-buffer prefetch FIRST (latency hides under the flag spin)
      const float4 sc = stepc[t];
      const int pos = t & (SS - 1);
      float shv[4], scv[4];
      #pragma unroll
      for (int rg = 0; rg < 4; ++rg) {
        int bx = pos * BH + eidx[rg];
        shv[rg] = bh[bx];
        scv[rg] = bc[bx];
      }

      if (t > 0) {
        // lanes 0/1 poll stripes 2wv/2wv+1; wave0 lane2 guards slot ring
        int fidx = -1, target = t;
        if (lane < 2) fidx = (2 * wv + lane) * FSTRIDE;
        else if (wv == 0 && lane == 2 && t >= 4) { fidx = 8 * FSTRIDE; target = t - 3; }
        if (fidx >= 0) {
          while (__hip_atomic_load(&gflag[fidx], __ATOMIC_RELAXED,
                                   __HIP_MEMORY_SCOPE_AGENT) < target) {}
        }
        const unsigned* Xs = X + (size_t)(((t - 1) & 3) * NGRP + grp) * XSLOT_U32;
        stage_stripe(Xs, 2 * wv,     LdsA, lane);
        stage_stripe(Xs, 2 * wv + 1, LdsA, lane);
      }
      __syncthreads();                  // barrier #1: all stripes staged

      f32x4 acc[4];
      #pragma unroll
      for (int g = 0; g < 4; ++g)
        #pragma unroll
        for (int i = 0; i < 4; ++i) acc[g][i] = 0.f;
      if (t == 0) {
        const f16* arh = x0hi + (size_t)(b0 + r16) * DD;
        const f16* arl = x0lo + (size_t)(b0 + r16) * DD;
        #pragma unroll
        for (int ks = 0; ks < 8; ++ks) {          // K=256: x0 @ W_ih^T
          int ko = ks * 32 + ksel;
          f16x8 ah = *(const f16x8*)(arh + ko);
          f16x8 al = *(const f16x8*)(arl + ko);
          #pragma unroll
          for (int g = 0; g < 4; ++g) {
            f16x8 w = *(const f16x8*)(Wih16 + (size_t)rowG[g] * DD + ko);
            acc[g] = __builtin_amdgcn_mfma_f32_16x16x32_f16(ah, w, acc[g], 0, 0, 0);
            acc[g] = __builtin_amdgcn_mfma_f32_16x16x32_f16(al, w, acc[g], 0, 0, 0);
          }
        }
        const f16* brh = h0hi + (size_t)(b0 + r16) * HH;
        const f16* brl = h0lo + (size_t)(b0 + r16) * HH;
        #pragma unroll
        for (int ks = 0; ks < 16; ++ks) {         // K=512: h0 @ W_hh^T
          int ko = ks * 32 + ksel;
          f16x8 ah = *(const f16x8*)(brh + ko);
          f16x8 al = *(const f16x8*)(brl + ko);
          #pragma unroll
          for (int g = 0; g < 4; ++g) {
            f16x8 w = *(const f16x8*)(Whh16 + (size_t)rowG[g] * HH + ko);
            acc[g] = __builtin_amdgcn_mfma_f32_16x16x32_f16(ah, w, acc[g], 0, 0, 0);
            acc[g] = __builtin_amdgcn_mfma_f32_16x16x32_f16(al, w, acc[g], 0, 0, 0);
          }
        }
      } else {
        gemm4(wreg, LdsA, lane, acc);
      }

      // ---- register-local epilogue: all 4 gates live in this lane ----
      const float a1 = sc.x, a2 = sc.y, nrm = sc.z;
      float baI = bI, baF = bF, baG = bG, baO = bO;
      if (t == 0) {
        baI = bias0[jg];        baF = bias0[512 + jg];
        baG = bias0[1024 + jg]; baO = bias0[1536 + jg];
      }
      unsigned* Xw = X + (size_t)((t & 3) * NGRP + grp) * XSLOT_U32;
      float hnv[4], cnv[4], chv[4];
      #pragma unroll
      for (int rg = 0; rg < 4; ++rg) {
        float pi = acc[0][rg] + baI;
        float pf = acc[1][rg] + baF;
        float pg = acc[2][rg] + baG;
        float po = acc[3][rg] + baO;
        float i_ = sigm(pi), f_ = sigm(pf), o_ = sigm(po), g_ = ftanh(pg);
        float cnew = fmaf(f_, creg[rg], i_ * g_);
        float hnew = o_ * ftanh(cnew);
        float ch = (a1 * hnew + a2 * ftanh(shv[rg])) * nrm;
        hnv[rg] = hnew; cnv[rg] = cnew; chv[rg] = ch;
        f16 hv = (f16)ch;
        unsigned hb = (unsigned)*(const unsigned short*)&hv;
        unsigned part = (unsigned)__shfl_xor((int)hb, 1);
        if ((r16 & 1) == 0)
          __hip_atomic_store(&Xw[role * 512 + (kc * 4 + rg) * 32 + (jl >> 1)],
                             hb | (part << 16),
                             __ATOMIC_RELAXED, __HIP_MEMORY_SCOPE_AGENT);
      }
      __syncthreads();                 // barrier #2: X stores drained (vmcnt 0)
      if (tid == 0)
        __hip_atomic_store(&gflag[role * FSTRIDE], t + 1, __ATOMIC_RELAXED,
                           __HIP_MEMORY_SCOPE_AGENT);

      // epilogue phase 2 (off critical path): cc, skip buffers, finals
      #pragma unroll
      for (int rg = 0; rg < 4; ++rg) {
        float cc = (a1 * cnv[rg] + a2 * ftanh(scv[rg])) * nrm;
        creg[rg] = cc;
        int bx = pos * BH + eidx[rg];
        bh[bx] = hnv[rg];
        bc[bx] = cnv[rg];
        if (t == TT - 1) {
          __builtin_nontemporal_store(chv[rg], &outp[OUT_BASE + eidx[rg]]);       // h_fin
          __builtin_nontemporal_store(cc,      &outp[OUT_BASE + BH + eidx[rg]]);  // c_fin
        }
      }
    }
  } else {
    // ---------- lagging out-projection block (one per group) ----------
    float bld[4];
    #pragma unroll
    for (int g = 0; g < 4; ++g) bld[g] = b_lin[rowG[g]];
    for (int s = 0; s < TT; ++s) {
      // lanes 0/1 poll stripes 2wv/2wv+1, then stage them
      if (lane < 2) {
        int fidx = (2 * wv + lane) * FSTRIDE;
        while (__hip_atomic_load(&gflag[fidx], __ATOMIC_RELAXED,
                                 __HIP_MEMORY_SCOPE_AGENT) < s + 1) {}
      }
      const unsigned* Xs = X + (size_t)((s & 3) * NGRP + grp) * XSLOT_U32;
      stage_stripe(Xs, 2 * wv,     LdsA, lane);
      stage_stripe(Xs, 2 * wv + 1, LdsA, lane);
      __syncthreads();                 // staging complete (vmcnt drained)
      if (tid == 0)                    // EARLY slot release: staged == consumed
        __hip_atomic_store(&gflag[8 * FSTRIDE], s + 1, __ATOMIC_RELAXED,
                           __HIP_MEMORY_SCOPE_AGENT);
      f32x4 acc[4];
      #pragma unroll
      for (int g = 0; g < 4; ++g)
        #pragma unroll
        for (int i = 0; i < 4; ++i) acc[g][i] = 0.f;
      gemm4(wreg, LdsA, lane, acc);
      const size_t srow = (size_t)s * DD;
      #pragma unroll
      for (int g = 0; g < 4; ++g)
        #pragma unroll
        for (int rg = 0; rg < 4; ++rg)
          __builtin_nontemporal_store(acc[g][rg] + bld[g],
              &outp[(size_t)(b0 + kc * 4 + rg) * (TT*DD) + srow + rowG[g]]);
      __syncthreads();                 // all waves done reading LdsA before next stage
    }
  }
}

// ---------------- host launch ----------------

extern "C" void kernel_launch(void* const* d_in, const int* in_sizes, int n_in,
                              void* d_out, int out_size, void* d_ws, size_t ws_size,
                              hipStream_t stream)
{
  const float* x0    = (const float*)d_in[0];
  const float* h0    = (const float*)d_in[1];
  const float* c0    = (const float*)d_in[2];
  const float* W_ih  = (const float*)d_in[3];
  const float* W_hh  = (const float*)d_in[4];
  const float* b_ih  = (const float*)d_in[5];
  const float* b_hh  = (const float*)d_in[6];
  const float* W_lin = (const float*)d_in[7];
  const float* b_lin = (const float*)d_in[8];
  const int*   w1    = (const int*)d_in[9];
  const int*   w2    = (const int*)d_in[10];

  char* p = (char*)d_ws;
  f16* Wbig16 = (f16*)p;            p += (size_t)G4H*HH*2;
  f16* Wih16  = (f16*)p;            p += (size_t)G4H*DD*2;
  f16* Whh16  = (f16*)p;            p += (size_t)G4H*HH*2;
  f16* Wlin16 = (f16*)p;            p += (size_t)DD*HH*2;
  f16* x0hi   = (f16*)p;            p += (size_t)BB*DD*2;
  f16* x0lo   = (f16*)p;            p += (size_t)BB*DD*2;
  f16* h0hi   = (f16*)p;            p += (size_t)BH*2;
  f16* h0lo   = (f16*)p;            p += (size_t)BH*2;
  unsigned* X = (unsigned*)p;       p += (size_t)4*NGRP*XSLOT_U32*4;   // 1 MB
  float* bh   = (float*)p;          p += (size_t)SS*BH*4;
  float* bc   = (float*)p;          p += (size_t)SS*BH*4;
  float* bias0= (float*)p;          p += G4H*4;
  float* bias1= (float*)p;          p += G4H*4;
  float4* stepc = (float4*)p;       p += (size_t)TT*16;
  int*  flags = (int*)p;            p += 4096*4;
  float* outp = (float*)d_out;

  hipLaunchKernelGGL(prep_wbig16, dim3(32, 8), dim3(256), 0, stream,
                     W_ih, W_hh, W_lin, Wbig16);
  hipLaunchKernelGGL(prep_bias, dim3(8), dim3(256), 0, stream,
                     b_ih, b_hh, W_ih, b_lin, bias0, bias1);
  hipLaunchKernelGGL(prep_cvtw, dim3(6656), dim3(256), 0, stream,
                     W_ih, W_hh, W_lin, Wih16, Whh16, Wlin16);
  hipLaunchKernelGGL(prep_init, dim3(4096), dim3(256), 0, stream,
                     x0, h0, c0, w1, w2, bh, bc, x0hi, x0lo, h0hi, h0lo, stepc, flags);

  hipLaunchKernelGGL(lstm_persist, dim3(128 + NGRP), dim3(256), 0, stream,
                     x0hi, x0lo, h0hi, h0lo, c0, Wih16, Whh16, Wbig16, Wlin16,
                     bias0, bias1, b_lin, stepc, X, bh, bc, flags, outp);
}